// Round 1
// baseline (3050.437 us; speedup 1.0000x reference)
//
#include <hip/hip_runtime.h>
#include <hip/hip_bf16.h>
#include <stdint.h>
#include <stddef.h>

#define VOCAB 32000
#define HID 256
#define BATCH 16
#define SEQ 256
#define TSTEPS 255          // S-1
#define NGATES 1024         // 4*HID
#define NWG 4               // scan workgroups (each owns 64 hidden units)
#define MROWS (TSTEPS*BATCH) // 4080

typedef __attribute__((ext_vector_type(8))) __bf16 bf16x8;
typedef __attribute__((ext_vector_type(8))) short short8;
typedef __attribute__((ext_vector_type(4))) float floatx4;

__device__ __forceinline__ float sigmoidf_(float x) {
    return 1.0f / (1.0f + __expf(-x));
}
__device__ __forceinline__ float tanhf_(float x) {
    return 2.0f / (1.0f + __expf(-2.0f * x)) - 1.0f;
}

// load 8 consecutive f32 (32B-aligned) -> bf16x8 fragment
__device__ __forceinline__ bf16x8 cvt8(const float* __restrict__ p) {
    const floatx4* q = (const floatx4*)p;
    floatx4 x = q[0], y = q[1];
    bf16x8 r;
    r[0] = (__bf16)x[0]; r[1] = (__bf16)x[1]; r[2] = (__bf16)x[2]; r[3] = (__bf16)x[3];
    r[4] = (__bf16)y[0]; r[5] = (__bf16)y[1]; r[6] = (__bf16)y[2]; r[7] = (__bf16)y[3];
    return r;
}

// step-tag for self-validating packed h words.
// hi/lo bytes always differ (0xC3 != 0x5A), so no uniform-byte workspace
// poison pattern (0x00.., 0xFF.., 0xCB.., ...) can alias any tag.
__device__ __forceinline__ uint32_t tag16(int t) {
    return (uint32_t)((((t ^ 0xC3) & 0xFF) << 8) | ((t ^ 0x5A) & 0xFF));
}

// ---------------- K0: f32 -> bf16 convert (W_lin, W_ih) ----------------
__global__ __launch_bounds__(256) void k_cvt(const float* __restrict__ src,
                                             __bf16* __restrict__ dst) {
    size_t i = ((size_t)blockIdx.x * 256 + threadIdx.x) * 8;
    bf16x8 r = cvt8(src + i);
    *(bf16x8*)(dst + i) = r;
}

// ---------------- K1: xw[t][n][b] = emb_eff[tok[b][t]] @ W_ih.T + b_ih + b_hh
// one block per t; 4 waves; wave w covers n in [w*256, w*256+256)
// xw stored in MFMA C-layout-friendly order: [t][n][b] (b innermost)
__global__ __launch_bounds__(256) void k_xw(const int* __restrict__ old,
                                            const float* __restrict__ emb,
                                            const __bf16* __restrict__ wih,
                                            const float* __restrict__ b_ih,
                                            const float* __restrict__ b_hh,
                                            float* __restrict__ xw) {
    int t = blockIdx.x;
    int tid = threadIdx.x;
    int wave = tid >> 6, lane = tid & 63, quad = lane >> 4, l16 = lane & 15;

    // A fragments: x[b=l16][k], k = kt*32 + quad*8 + j
    int tok = old[l16 * SEQ + t];
    bf16x8 a[8];
#pragma unroll
    for (int kt = 0; kt < 8; kt++) {
        if (tok == 0) {
            bf16x8 z;
#pragma unroll
            for (int j = 0; j < 8; j++) z[j] = (__bf16)0.0f;
            a[kt] = z;
        } else {
            a[kt] = cvt8(emb + (size_t)tok * HID + kt * 32 + quad * 8);
        }
    }

    float* xwt = xw + (size_t)t * NGATES * BATCH;
    for (int nt = 0; nt < 16; nt++) {
        int n = wave * 256 + nt * 16 + l16;
        floatx4 acc = {0.0f, 0.0f, 0.0f, 0.0f};
#pragma unroll
        for (int kt = 0; kt < 8; kt++) {
            bf16x8 bf = *(const bf16x8*)(wih + (size_t)n * HID + kt * 32 + quad * 8);
            acc = __builtin_amdgcn_mfma_f32_16x16x32_bf16(a[kt], bf, acc, 0, 0, 0);
        }
        float bias = b_ih[n] + b_hh[n];
        acc[0] += bias; acc[1] += bias; acc[2] += bias; acc[3] += bias;
        // C layout: m(batch) = quad*4+r, n-col = l16 -> contiguous float4 over b
        *(floatx4*)(xwt + n * BATCH + quad * 4) = acc;
    }
}

// ---------------- K2: the LSTM scan ----------------
// 4 WGs x 256 threads. WG g owns hidden units [64g, 64g+64); wave w owns 16.
// W_hh fragments (bf16) live in VGPRs for the whole scan (128 VGPR/wave).
//
// Cross-WG h exchange is FENCE-FREE: each h value is published as a 32-bit
// word (tag(t)<<16)|bf16(h) via relaxed agent-scope atomic stores
// (write-through to the coherence point). Consumers issue relaxed
// agent-scope 64-bit atomic loads (which bypass stale L1/L2) and retry
// until every word carries the expected tag. Each word self-validates, so
// no release/acquire fences, no flag cacheline contention, no barriers.
// Slots are write-once per t -> deadlock-free by construction.
// A plain bf16 copy of h is also stored (hbuf) for k_proj, unchanged.
__global__ __launch_bounds__(256, 1) void k_scan(const float* __restrict__ W_hh,
                                                 const float* __restrict__ xw,
                                                 __bf16* __restrict__ hbuf,
                                                 uint32_t* __restrict__ hpk) {
    int wg = blockIdx.x;
    int tid = threadIdx.x;
    int wave = tid >> 6, lane = tid & 63, quad = lane >> 4, l16 = lane & 15;
    int j0 = wg * 64 + wave * 16;
    int jj = j0 + l16;  // this lane's hidden-unit column

    // Preload B fragments: B[k][n] = W_hh[gate*256 + jj][k]
    bf16x8 wf[4][8];
#pragma unroll
    for (int g = 0; g < 4; g++) {
        const float* wrow = W_hh + (size_t)(g * HID + jj) * HID;
#pragma unroll
        for (int kt = 0; kt < 8; kt++)
            wf[g][kt] = cvt8(wrow + kt * 32 + quad * 8);
    }

    // publish slot 0 (h = 0, tag(0)) — each WG covers its own 64 columns
    {
        uint32_t z = tag16(0) << 16;
#pragma unroll
        for (int r = 0; r < 4; r++)
            __hip_atomic_store(hpk + (quad * 4 + r) * HID + jj, z,
                               __ATOMIC_RELAXED, __HIP_MEMORY_SCOPE_AGENT);
    }

    float cr0 = 0.0f, cr1 = 0.0f, cr2 = 0.0f, cr3 = 0.0f;  // c, b = quad*4 + r

    // xw accumulator init, software-pipelined one step ahead so the HBM
    // latency hides under the h-poll
    floatx4 accN[4];
#pragma unroll
    for (int g = 0; g < 4; g++)
        accN[g] = *(const floatx4*)(xw + (size_t)(g * HID + jj) * BATCH + quad * 4);

    for (int t = 0; t < TSTEPS; t++) {
        floatx4 acc[4];
#pragma unroll
        for (int g = 0; g < 4; g++) acc[g] = accN[g];
        if (t + 1 < TSTEPS) {
            const float* xwn = xw + (size_t)(t + 1) * NGATES * BATCH;
#pragma unroll
            for (int g = 0; g < 4; g++)
                accN[g] = *(const floatx4*)(xwn + (size_t)(g * HID + jj) * BATCH + quad * 4);
        }

        // poll packed h for step t: A-frag words k = kt*32 + quad*8 + j, row b=l16
        const uint32_t* hp = hpk + (size_t)t * (BATCH * HID) + l16 * HID + quad * 8;
        uint32_t texp = tag16(t);
        unsigned long long wq[8][4];
        uint32_t bad;
        do {
#pragma unroll
            for (int kt = 0; kt < 8; kt++)
#pragma unroll
                for (int p = 0; p < 4; p++)
                    wq[kt][p] = __hip_atomic_load(
                        (const unsigned long long*)(hp + kt * 32 + p * 2),
                        __ATOMIC_RELAXED, __HIP_MEMORY_SCOPE_AGENT);
            bad = 0;
#pragma unroll
            for (int kt = 0; kt < 8; kt++)
#pragma unroll
                for (int p = 0; p < 4; p++) {
                    uint32_t w0 = (uint32_t)wq[kt][p];
                    uint32_t w1 = (uint32_t)(wq[kt][p] >> 32);
                    bad |= (w0 >> 16) ^ texp;
                    bad |= (w1 >> 16) ^ texp;
                }
        } while (bad);

        // extract bf16 A fragments from the packed words
        bf16x8 a[8];
#pragma unroll
        for (int kt = 0; kt < 8; kt++) {
            union { uint32_t u[4]; bf16x8 v; } cv;
#pragma unroll
            for (int p = 0; p < 4; p++) {
                uint32_t w0 = (uint32_t)wq[kt][p];
                uint32_t w1 = (uint32_t)(wq[kt][p] >> 32);
                cv.u[p] = (w0 & 0xFFFFu) | (w1 << 16);
            }
            a[kt] = cv.v;
        }

#pragma unroll
        for (int g = 0; g < 4; g++)
#pragma unroll
            for (int kt = 0; kt < 8; kt++)
                acc[g] = __builtin_amdgcn_mfma_f32_16x16x32_bf16(a[kt], wf[g][kt], acc[g], 0, 0, 0);

        // elementwise gates; acc[0]=i, acc[1]=f, acc[2]=g, acc[3]=o
        __bf16*   hout = hbuf + (size_t)(t + 1) * (BATCH * HID);
        uint32_t* hpo  = hpk  + (size_t)(t + 1) * (BATCH * HID);
        uint32_t  otag = tag16(t + 1) << 16;
        float c[4] = {cr0, cr1, cr2, cr3};
#pragma unroll
        for (int r = 0; r < 4; r++) {
            float iv = sigmoidf_(acc[0][r]);
            float fv = sigmoidf_(acc[1][r]);
            float gv = tanhf_(acc[2][r]);
            float ov = sigmoidf_(acc[3][r]);
            float cn = fv * c[r] + iv * gv;
            float h = ov * tanhf_(cn);
            c[r] = cn;
            __bf16 hb = (__bf16)h;
            hout[(quad * 4 + r) * HID + jj] = hb;      // plain store for k_proj
            union { __bf16 b; uint16_t u; } cvb; cvb.b = hb;
            __hip_atomic_store(hpo + (quad * 4 + r) * HID + jj,
                               otag | (uint32_t)cvb.u,
                               __ATOMIC_RELAXED, __HIP_MEMORY_SCOPE_AGENT);
        }
        cr0 = c[0]; cr1 = c[1]; cr2 = c[2]; cr3 = c[3];
    }
}

// ---------------- K3: logits = hs @ W_lin.T + b_lin ----------------
// M=4080 (rows = t*16+b, stored at hbuf row m+16), N=32000, K=256
// 128x128 tile, 256 threads (2x2 waves of 64x64), K staged in 4 chunks of 64
#define K3_MT 128
#define K3_NT 128
#define K3_KC 64
#define K3_LDR 72  // shorts per LDS row (+8 pad -> 2-way-max bank aliasing, free)

__global__ __launch_bounds__(256) void k_proj(const __bf16* __restrict__ hbuf,
                                              const __bf16* __restrict__ wl,
                                              const float* __restrict__ b_lin,
                                              float* __restrict__ out) {
    __shared__ short lA[K3_MT * K3_LDR];
    __shared__ short lB[K3_NT * K3_LDR];

    int tid = threadIdx.x;
    int wave = tid >> 6, lane = tid & 63, quad = lane >> 4, l16 = lane & 15;
    int wm = wave >> 1, wn = wave & 1;
    int m0 = blockIdx.y * K3_MT;
    int n0 = blockIdx.x * K3_NT;

    floatx4 acc[4][4];
#pragma unroll
    for (int i = 0; i < 4; i++)
#pragma unroll
        for (int j = 0; j < 4; j++)
            acc[i][j] = (floatx4){0.0f, 0.0f, 0.0f, 0.0f};

    const __bf16* Abase = hbuf + (size_t)BATCH * HID;  // row m -> slot rows m+16

    int srow = tid >> 1;         // 0..127
    int scol = (tid & 1) * 32;   // shorts within the 64-wide K chunk

    for (int kc = 0; kc < 4; kc++) {
        int kbase = kc * K3_KC;
        // stage A (guard m < 4080)
        {
            int m = m0 + srow;
            const __bf16* src = Abase + (size_t)m * HID + kbase + scol;
#pragma unroll
            for (int i = 0; i < 4; i++) {
                short8 v = (short8)0;
                if (m < MROWS) v = *(const short8*)(src + i * 8);
                *(short8*)&lA[srow * K3_LDR + scol + i * 8] = v;
            }
        }
        // stage B
        {
            const __bf16* src = wl + (size_t)(n0 + srow) * HID + kbase + scol;
#pragma unroll
            for (int i = 0; i < 4; i++)
                *(short8*)&lB[srow * K3_LDR + scol + i * 8] = *(const short8*)(src + i * 8);
        }
        __syncthreads();
#pragma unroll
        for (int kt = 0; kt < 2; kt++) {
            int ko = kt * 32 + quad * 8;
            bf16x8 af[4], bf[4];
#pragma unroll
            for (int mt = 0; mt < 4; mt++)
                af[mt] = *(bf16x8*)&lA[(wm * 64 + mt * 16 + l16) * K3_LDR + ko];
#pragma unroll
            for (int nt = 0; nt < 4; nt++)
                bf[nt] = *(bf16x8*)&lB[(wn * 64 + nt * 16 + l16) * K3_LDR + ko];
#pragma unroll
            for (int mt = 0; mt < 4; mt++)
#pragma unroll
                for (int nt = 0; nt < 4; nt++)
                    acc[mt][nt] = __builtin_amdgcn_mfma_f32_16x16x32_bf16(
                        af[mt], bf[nt], acc[mt][nt], 0, 0, 0);
        }
        __syncthreads();
    }

    // epilogue: out[b][t][v], m = t*16 + b
#pragma unroll
    for (int nt = 0; nt < 4; nt++) {
        int n = n0 + wn * 64 + nt * 16 + l16;
        float bias = b_lin[n];
#pragma unroll
        for (int mt = 0; mt < 4; mt++) {
            int mbase = m0 + wm * 64 + mt * 16 + quad * 4;
#pragma unroll
            for (int r = 0; r < 4; r++) {
                int m = mbase + r;
                if (m < MROWS) {
                    int b = m & 15, t = m >> 4;
                    out[(size_t)b * TSTEPS * VOCAB + (size_t)t * VOCAB + n] =
                        acc[mt][nt][r] + bias;
                }
            }
        }
    }
}

// ---------------- launch ----------------
extern "C" void kernel_launch(void* const* d_in, const int* in_sizes, int n_in,
                              void* d_out, int out_size, void* d_ws, size_t ws_size,
                              hipStream_t stream) {
    const int*   old   = (const int*)d_in[0];
    const float* emb   = (const float*)d_in[1];
    const float* W_ih  = (const float*)d_in[2];
    const float* W_hh  = (const float*)d_in[3];
    const float* b_ih  = (const float*)d_in[4];
    const float* b_hh  = (const float*)d_in[5];
    const float* W_lin = (const float*)d_in[6];
    const float* b_lin = (const float*)d_in[7];
    float* out = (float*)d_out;

    char* ws = (char*)d_ws;
    // ws layout (all 16B aligned)
    float*    xw   = (float*)ws;                                   // 255*1024*16*4 = 16,711,680
    __bf16*   wl   = (__bf16*)(ws + 16711680);                     // 32000*256*2   = 16,384,000
    __bf16*   wih  = (__bf16*)(ws + 16711680 + 16384000);          // 1024*256*2    =    524,288
    __bf16*   hbuf = (__bf16*)(ws + 16711680 + 16384000 + 524288); // 256*4096*2    =  2,097,152
    uint32_t* hpk  = (uint32_t*)(ws + 16711680 + 16384000 + 524288 + 2097152); // 256*4096*4 = 4,194,304

    // no memsets needed: packed slot 0 is published (tagged) by k_scan's
    // prologue, and poison cannot alias any tag16 value.
    k_cvt<<<dim3(VOCAB * HID / 2048), dim3(256), 0, stream>>>(W_lin, wl);
    k_cvt<<<dim3(NGATES * HID / 2048), dim3(256), 0, stream>>>(W_ih, wih);
    k_xw<<<dim3(TSTEPS), dim3(256), 0, stream>>>(old, emb, wih, b_ih, b_hh, xw);
    k_scan<<<dim3(NWG), dim3(256), 0, stream>>>(W_hh, xw, hbuf, hpk);
    k_proj<<<dim3(VOCAB / K3_NT, (MROWS + K3_MT - 1) / K3_MT), dim3(256), 0, stream>>>(
        hbuf, wl, b_lin, out);
}

// Round 2
// 1830.828 us; speedup vs baseline: 1.6662x; 1.6662x over previous
//
#include <hip/hip_runtime.h>
#include <hip/hip_bf16.h>
#include <stdint.h>
#include <stddef.h>

#define VOCAB 32000
#define HID 256
#define BATCH 16
#define SEQ 256
#define TSTEPS 255          // S-1
#define NGATES 1024         // 4*HID
#define NWG 4               // scan workgroups (each owns 64 hidden units)
#define MROWS (TSTEPS*BATCH) // 4080

typedef __attribute__((ext_vector_type(8))) __bf16 bf16x8;
typedef __attribute__((ext_vector_type(8))) short short8;
typedef __attribute__((ext_vector_type(4))) float floatx4;
typedef __attribute__((ext_vector_type(4))) uint32_t uint32x4;

__device__ __forceinline__ float sigmoidf_(float x) {
    return 1.0f / (1.0f + __expf(-x));
}
__device__ __forceinline__ float tanhf_(float x) {
    return 2.0f / (1.0f + __expf(-2.0f * x)) - 1.0f;
}

// load 8 consecutive f32 (32B-aligned) -> bf16x8 fragment
__device__ __forceinline__ bf16x8 cvt8(const float* __restrict__ p) {
    const floatx4* q = (const floatx4*)p;
    floatx4 x = q[0], y = q[1];
    bf16x8 r;
    r[0] = (__bf16)x[0]; r[1] = (__bf16)x[1]; r[2] = (__bf16)x[2]; r[3] = (__bf16)x[3];
    r[4] = (__bf16)y[0]; r[5] = (__bf16)y[1]; r[6] = (__bf16)y[2]; r[7] = (__bf16)y[3];
    return r;
}

// step-tag for self-validating packed h words.
// hi/lo bytes always differ (0xC3 != 0x5A), so no uniform-byte workspace
// poison pattern (0x00.., 0xFF.., 0xCB.., ...) can alias any tag.
__device__ __forceinline__ uint32_t tag16(int t) {
    return (uint32_t)((((t ^ 0xC3) & 0xFF) << 8) | ((t ^ 0x5A) & 0xFF));
}

// ---------------- K0: f32 -> bf16 convert (W_lin, W_ih) ----------------
__global__ __launch_bounds__(256) void k_cvt(const float* __restrict__ src,
                                             __bf16* __restrict__ dst) {
    size_t i = ((size_t)blockIdx.x * 256 + threadIdx.x) * 8;
    bf16x8 r = cvt8(src + i);
    *(bf16x8*)(dst + i) = r;
}

// ---------------- K1: xw[t][n][b] = emb_eff[tok[b][t]] @ W_ih.T + b_ih + b_hh
// one block per t; 4 waves; wave w covers n in [w*256, w*256+256)
// xw stored in MFMA C-layout-friendly order: [t][n][b] (b innermost)
__global__ __launch_bounds__(256) void k_xw(const int* __restrict__ old,
                                            const float* __restrict__ emb,
                                            const __bf16* __restrict__ wih,
                                            const float* __restrict__ b_ih,
                                            const float* __restrict__ b_hh,
                                            float* __restrict__ xw) {
    int t = blockIdx.x;
    int tid = threadIdx.x;
    int wave = tid >> 6, lane = tid & 63, quad = lane >> 4, l16 = lane & 15;

    // A fragments: x[b=l16][k], k = kt*32 + quad*8 + j
    int tok = old[l16 * SEQ + t];
    bf16x8 a[8];
#pragma unroll
    for (int kt = 0; kt < 8; kt++) {
        if (tok == 0) {
            bf16x8 z;
#pragma unroll
            for (int j = 0; j < 8; j++) z[j] = (__bf16)0.0f;
            a[kt] = z;
        } else {
            a[kt] = cvt8(emb + (size_t)tok * HID + kt * 32 + quad * 8);
        }
    }

    float* xwt = xw + (size_t)t * NGATES * BATCH;
    for (int nt = 0; nt < 16; nt++) {
        int n = wave * 256 + nt * 16 + l16;
        floatx4 acc = {0.0f, 0.0f, 0.0f, 0.0f};
#pragma unroll
        for (int kt = 0; kt < 8; kt++) {
            bf16x8 bf = *(const bf16x8*)(wih + (size_t)n * HID + kt * 32 + quad * 8);
            acc = __builtin_amdgcn_mfma_f32_16x16x32_bf16(a[kt], bf, acc, 0, 0, 0);
        }
        float bias = b_ih[n] + b_hh[n];
        acc[0] += bias; acc[1] += bias; acc[2] += bias; acc[3] += bias;
        // C layout: m(batch) = quad*4+r, n-col = l16 -> contiguous float4 over b
        *(floatx4*)(xwt + n * BATCH + quad * 4) = acc;
    }
}

// ---------------- K2: the LSTM scan ----------------
// 4 WGs x 256 threads. WG g owns hidden units [64g, 64g+64); wave w owns 16.
// W_hh fragments (bf16) live in VGPRs for the whole scan (128 VGPR/wave).
//
// Cross-WG h exchange is FENCE-FREE: each h value is published as a 32-bit
// word (tag(t)<<16)|bf16(h) via relaxed agent-scope atomic stores
// (write-through to the coherence point). Consumers poll with ONE inline-asm
// batch of 16 global_load_dwordx4 (sc0 sc1 -> bypass L1/L2, all in flight
// simultaneously) + a single s_waitcnt vmcnt(0) INSIDE the asm block, then
// retry until every word carries the expected tag. Round 1 showed that
// __hip_atomic_load is serialized by the compiler (one vmcnt(0) per load ->
// 32 sequential fabric round trips, 9.1 us/step); the batched asm makes the
// poll a single round trip. Each word self-validates -> no fences, no flag
// cacheline, no barriers. Slots are write-once per t -> deadlock-free.
// A plain bf16 copy of h is also stored (hbuf) for k_proj, unchanged.
__global__ __launch_bounds__(256, 1) void k_scan(const float* __restrict__ W_hh,
                                                 const float* __restrict__ xw,
                                                 __bf16* __restrict__ hbuf,
                                                 uint32_t* __restrict__ hpk) {
    int wg = blockIdx.x;
    int tid = threadIdx.x;
    int wave = tid >> 6, lane = tid & 63, quad = lane >> 4, l16 = lane & 15;
    int j0 = wg * 64 + wave * 16;
    int jj = j0 + l16;  // this lane's hidden-unit column

    // Preload B fragments: B[k][n] = W_hh[gate*256 + jj][k]
    bf16x8 wf[4][8];
#pragma unroll
    for (int g = 0; g < 4; g++) {
        const float* wrow = W_hh + (size_t)(g * HID + jj) * HID;
#pragma unroll
        for (int kt = 0; kt < 8; kt++)
            wf[g][kt] = cvt8(wrow + kt * 32 + quad * 8);
    }

    // publish slot 0 (h = 0, tag(0)) — each WG covers its own 64 columns
    {
        uint32_t z = tag16(0) << 16;
#pragma unroll
        for (int r = 0; r < 4; r++)
            __hip_atomic_store(hpk + (quad * 4 + r) * HID + jj, z,
                               __ATOMIC_RELAXED, __HIP_MEMORY_SCOPE_AGENT);
    }

    float cr0 = 0.0f, cr1 = 0.0f, cr2 = 0.0f, cr3 = 0.0f;  // c, b = quad*4 + r

    // xw accumulator init, software-pipelined one step ahead so the HBM
    // latency hides under the h-poll
    floatx4 accN[4];
#pragma unroll
    for (int g = 0; g < 4; g++)
        accN[g] = *(const floatx4*)(xw + (size_t)(g * HID + jj) * BATCH + quad * 4);

    for (int t = 0; t < TSTEPS; t++) {
        floatx4 acc[4];
#pragma unroll
        for (int g = 0; g < 4; g++) acc[g] = accN[g];
        if (t + 1 < TSTEPS) {
            const float* xwn = xw + (size_t)(t + 1) * NGATES * BATCH;
#pragma unroll
            for (int g = 0; g < 4; g++)
                accN[g] = *(const floatx4*)(xwn + (size_t)(g * HID + jj) * BATCH + quad * 4);
        }

        // poll packed h for step t: this lane needs words
        // k = kt*32 + quad*8 + {0..7}, row b = l16  (8 kt x 32 bytes)
        const uint32_t* hp = hpk + (size_t)t * (BATCH * HID) + l16 * HID + quad * 8;
        uint32_t texpw = tag16(t) << 16;
        uint32x4 q[16];  // q[kt*2+p2] = words p2*4..p2*4+3 of row-slice kt
        uint32_t bad;
        do {
            asm volatile(
                "global_load_dwordx4 %0,  %16, off sc0 sc1\n\t"
                "global_load_dwordx4 %1,  %16, off offset:16  sc0 sc1\n\t"
                "global_load_dwordx4 %2,  %16, off offset:128 sc0 sc1\n\t"
                "global_load_dwordx4 %3,  %16, off offset:144 sc0 sc1\n\t"
                "global_load_dwordx4 %4,  %16, off offset:256 sc0 sc1\n\t"
                "global_load_dwordx4 %5,  %16, off offset:272 sc0 sc1\n\t"
                "global_load_dwordx4 %6,  %16, off offset:384 sc0 sc1\n\t"
                "global_load_dwordx4 %7,  %16, off offset:400 sc0 sc1\n\t"
                "global_load_dwordx4 %8,  %16, off offset:512 sc0 sc1\n\t"
                "global_load_dwordx4 %9,  %16, off offset:528 sc0 sc1\n\t"
                "global_load_dwordx4 %10, %16, off offset:640 sc0 sc1\n\t"
                "global_load_dwordx4 %11, %16, off offset:656 sc0 sc1\n\t"
                "global_load_dwordx4 %12, %16, off offset:768 sc0 sc1\n\t"
                "global_load_dwordx4 %13, %16, off offset:784 sc0 sc1\n\t"
                "global_load_dwordx4 %14, %16, off offset:896 sc0 sc1\n\t"
                "global_load_dwordx4 %15, %16, off offset:912 sc0 sc1\n\t"
                "s_waitcnt vmcnt(0)"
                : "=v"(q[0]), "=v"(q[1]), "=v"(q[2]), "=v"(q[3]),
                  "=v"(q[4]), "=v"(q[5]), "=v"(q[6]), "=v"(q[7]),
                  "=v"(q[8]), "=v"(q[9]), "=v"(q[10]), "=v"(q[11]),
                  "=v"(q[12]), "=v"(q[13]), "=v"(q[14]), "=v"(q[15])
                : "v"(hp)
                : "memory");
            uint32_t accor = 0;
#pragma unroll
            for (int i = 0; i < 16; i++)
#pragma unroll
                for (int e = 0; e < 4; e++)
                    accor |= q[i][e] ^ texpw;
            bad = accor & 0xFFFF0000u;
        } while (bad);

        // extract bf16 A fragments from the packed words
        bf16x8 a[8];
#pragma unroll
        for (int kt = 0; kt < 8; kt++) {
            union { uint32_t u[4]; bf16x8 v; } cv;
#pragma unroll
            for (int p = 0; p < 4; p++) {
                uint32_t w0 = q[kt * 2 + (p >> 1)][(p & 1) * 2];
                uint32_t w1 = q[kt * 2 + (p >> 1)][(p & 1) * 2 + 1];
                cv.u[p] = (w0 & 0xFFFFu) | (w1 << 16);
            }
            a[kt] = cv.v;
        }

#pragma unroll
        for (int g = 0; g < 4; g++)
#pragma unroll
            for (int kt = 0; kt < 8; kt++)
                acc[g] = __builtin_amdgcn_mfma_f32_16x16x32_bf16(a[kt], wf[g][kt], acc[g], 0, 0, 0);

        // elementwise gates; acc[0]=i, acc[1]=f, acc[2]=g, acc[3]=o
        __bf16*   hout = hbuf + (size_t)(t + 1) * (BATCH * HID);
        uint32_t* hpo  = hpk  + (size_t)(t + 1) * (BATCH * HID);
        uint32_t  otag = tag16(t + 1) << 16;
        float c[4] = {cr0, cr1, cr2, cr3};
#pragma unroll
        for (int r = 0; r < 4; r++) {
            float iv = sigmoidf_(acc[0][r]);
            float fv = sigmoidf_(acc[1][r]);
            float gv = tanhf_(acc[2][r]);
            float ov = sigmoidf_(acc[3][r]);
            float cn = fv * c[r] + iv * gv;
            float h = ov * tanhf_(cn);
            c[r] = cn;
            __bf16 hb = (__bf16)h;
            hout[(quad * 4 + r) * HID + jj] = hb;      // plain store for k_proj
            union { __bf16 b; uint16_t u; } cvb; cvb.b = hb;
            __hip_atomic_store(hpo + (quad * 4 + r) * HID + jj,
                               otag | (uint32_t)cvb.u,
                               __ATOMIC_RELAXED, __HIP_MEMORY_SCOPE_AGENT);
        }
        cr0 = c[0]; cr1 = c[1]; cr2 = c[2]; cr3 = c[3];
    }
}

// ---------------- K3: logits = hs @ W_lin.T + b_lin ----------------
// M=4080 (rows = t*16+b, stored at hbuf row m+16), N=32000, K=256
// 128x128 tile, 256 threads (2x2 waves of 64x64), K staged in 4 chunks of 64
#define K3_MT 128
#define K3_NT 128
#define K3_KC 64
#define K3_LDR 72  // shorts per LDS row (+8 pad -> 2-way-max bank aliasing, free)

__global__ __launch_bounds__(256) void k_proj(const __bf16* __restrict__ hbuf,
                                              const __bf16* __restrict__ wl,
                                              const float* __restrict__ b_lin,
                                              float* __restrict__ out) {
    __shared__ short lA[K3_MT * K3_LDR];
    __shared__ short lB[K3_NT * K3_LDR];

    int tid = threadIdx.x;
    int wave = tid >> 6, lane = tid & 63, quad = lane >> 4, l16 = lane & 15;
    int wm = wave >> 1, wn = wave & 1;
    int m0 = blockIdx.y * K3_MT;
    int n0 = blockIdx.x * K3_NT;

    floatx4 acc[4][4];
#pragma unroll
    for (int i = 0; i < 4; i++)
#pragma unroll
        for (int j = 0; j < 4; j++)
            acc[i][j] = (floatx4){0.0f, 0.0f, 0.0f, 0.0f};

    const __bf16* Abase = hbuf + (size_t)BATCH * HID;  // row m -> slot rows m+16

    int srow = tid >> 1;         // 0..127
    int scol = (tid & 1) * 32;   // shorts within the 64-wide K chunk

    for (int kc = 0; kc < 4; kc++) {
        int kbase = kc * K3_KC;
        // stage A (guard m < 4080)
        {
            int m = m0 + srow;
            const __bf16* src = Abase + (size_t)m * HID + kbase + scol;
#pragma unroll
            for (int i = 0; i < 4; i++) {
                short8 v = (short8)0;
                if (m < MROWS) v = *(const short8*)(src + i * 8);
                *(short8*)&lA[srow * K3_LDR + scol + i * 8] = v;
            }
        }
        // stage B
        {
            const __bf16* src = wl + (size_t)(n0 + srow) * HID + kbase + scol;
#pragma unroll
            for (int i = 0; i < 4; i++)
                *(short8*)&lB[srow * K3_LDR + scol + i * 8] = *(const short8*)(src + i * 8);
        }
        __syncthreads();
#pragma unroll
        for (int kt = 0; kt < 2; kt++) {
            int ko = kt * 32 + quad * 8;
            bf16x8 af[4], bf[4];
#pragma unroll
            for (int mt = 0; mt < 4; mt++)
                af[mt] = *(bf16x8*)&lA[(wm * 64 + mt * 16 + l16) * K3_LDR + ko];
#pragma unroll
            for (int nt = 0; nt < 4; nt++)
                bf[nt] = *(bf16x8*)&lB[(wn * 64 + nt * 16 + l16) * K3_LDR + ko];
#pragma unroll
            for (int mt = 0; mt < 4; mt++)
#pragma unroll
                for (int nt = 0; nt < 4; nt++)
                    acc[mt][nt] = __builtin_amdgcn_mfma_f32_16x16x32_bf16(
                        af[mt], bf[nt], acc[mt][nt], 0, 0, 0);
        }
        __syncthreads();
    }

    // epilogue: out[b][t][v], m = t*16 + b
#pragma unroll
    for (int nt = 0; nt < 4; nt++) {
        int n = n0 + wn * 64 + nt * 16 + l16;
        float bias = b_lin[n];
#pragma unroll
        for (int mt = 0; mt < 4; mt++) {
            int mbase = m0 + wm * 64 + mt * 16 + quad * 4;
#pragma unroll
            for (int r = 0; r < 4; r++) {
                int m = mbase + r;
                if (m < MROWS) {
                    int b = m & 15, t = m >> 4;
                    out[(size_t)b * TSTEPS * VOCAB + (size_t)t * VOCAB + n] =
                        acc[mt][nt][r] + bias;
                }
            }
        }
    }
}

// ---------------- launch ----------------
extern "C" void kernel_launch(void* const* d_in, const int* in_sizes, int n_in,
                              void* d_out, int out_size, void* d_ws, size_t ws_size,
                              hipStream_t stream) {
    const int*   old   = (const int*)d_in[0];
    const float* emb   = (const float*)d_in[1];
    const float* W_ih  = (const float*)d_in[2];
    const float* W_hh  = (const float*)d_in[3];
    const float* b_ih  = (const float*)d_in[4];
    const float* b_hh  = (const float*)d_in[5];
    const float* W_lin = (const float*)d_in[6];
    const float* b_lin = (const float*)d_in[7];
    float* out = (float*)d_out;

    char* ws = (char*)d_ws;
    // ws layout (all 16B aligned)
    float*    xw   = (float*)ws;                                   // 255*1024*16*4 = 16,711,680
    __bf16*   wl   = (__bf16*)(ws + 16711680);                     // 32000*256*2   = 16,384,000
    __bf16*   wih  = (__bf16*)(ws + 16711680 + 16384000);          // 1024*256*2    =    524,288
    __bf16*   hbuf = (__bf16*)(ws + 16711680 + 16384000 + 524288); // 256*4096*2    =  2,097,152
    uint32_t* hpk  = (uint32_t*)(ws + 16711680 + 16384000 + 524288 + 2097152); // 256*4096*4 = 4,194,304

    // no memsets needed: packed slot 0 is published (tagged) by k_scan's
    // prologue, and poison cannot alias any tag16 value.
    k_cvt<<<dim3(VOCAB * HID / 2048), dim3(256), 0, stream>>>(W_lin, wl);
    k_cvt<<<dim3(NGATES * HID / 2048), dim3(256), 0, stream>>>(W_ih, wih);
    k_xw<<<dim3(TSTEPS), dim3(256), 0, stream>>>(old, emb, wih, b_ih, b_hh, xw);
    k_scan<<<dim3(NWG), dim3(256), 0, stream>>>(W_hh, xw, hbuf, hpk);
    k_proj<<<dim3(VOCAB / K3_NT, (MROWS + K3_MT - 1) / K3_MT), dim3(256), 0, stream>>>(
        hbuf, wl, b_lin, out);
}